// Round 3
// baseline (464.895 us; speedup 1.0000x reference)
//
#include <hip/hip_runtime.h>

#define NN 100000
#define NE 1600000
#define NBLK_SCAN ((NN + 1023) / 1024)   // 98 blocks of 1024 elems
#define NBUCK ((NN + 31) / 32)           // 3125 buckets of 32 nodes

// ---------------------------------------------------------------------------
// edge_index dtype detection: if data is int64 (little-endian, values < 2^31),
// every odd 32-bit word of the first 2*NE words is zero.
__global__ void k_detect(const unsigned int* w, int* flag) {
    int i = blockIdx.x * blockDim.x + threadIdx.x;
    int stride = gridDim.x * blockDim.x;
    for (int idx = i; idx < NE; idx += stride) {
        if (w[2 * idx + 1] != 0u) { *flag = 1; return; }
    }
}

__global__ void k_degree(const void* ei, const int* __restrict__ flag,
                         int* __restrict__ deg) {
    int e = blockIdx.x * blockDim.x + threadIdx.x;
    if (e >= NE) return;
    int d = (*flag == 0) ? (int)((const long long*)ei)[NE + e]
                         : ((const int*)ei)[NE + e];
    atomicAdd(&deg[d], 1);
}

// ---------------------------------------------------------------------------
// Exclusive scan of deg -> rowptr (3 kernels)
__global__ __launch_bounds__(256) void k_scan1(const int* __restrict__ deg,
                                               int* __restrict__ ex,
                                               int* __restrict__ bsum) {
    __shared__ int lds[256];
    int b = blockIdx.x, t = threadIdx.x;
    int base = b * 1024 + t * 4;
    int v[4];
#pragma unroll
    for (int k = 0; k < 4; ++k) { int i = base + k; v[k] = (i < NN) ? deg[i] : 0; }
    int s = v[0] + v[1] + v[2] + v[3];
    lds[t] = s;
    __syncthreads();
    for (int off = 1; off < 256; off <<= 1) {
        int tmp = (t >= off) ? lds[t - off] : 0;
        __syncthreads();
        lds[t] += tmp;
        __syncthreads();
    }
    int run = lds[t] - s;
#pragma unroll
    for (int k = 0; k < 4; ++k) {
        int i = base + k;
        if (i < NN) ex[i] = run;
        run += v[k];
    }
    if (t == 255) bsum[b] = lds[255];
}

__global__ __launch_bounds__(128) void k_scan2(int* bsum) {
    __shared__ int lds[128];
    int t = threadIdx.x;
    int v = (t < NBLK_SCAN) ? bsum[t] : 0;
    lds[t] = v;
    __syncthreads();
    for (int off = 1; off < 128; off <<= 1) {
        int tmp = (t >= off) ? lds[t - off] : 0;
        __syncthreads();
        lds[t] += tmp;
        __syncthreads();
    }
    if (t < NBLK_SCAN) bsum[t] = lds[t] - v;  // exclusive
}

// rowptr + dinv + normalized x (xn = dinv * x) in one pass
__global__ void k_scan3(const int* __restrict__ ex, const int* __restrict__ bsum,
                        const int* __restrict__ deg, const float* __restrict__ x,
                        int* __restrict__ rowptr, float* __restrict__ dinv,
                        float2* __restrict__ xn) {
    int i = blockIdx.x * blockDim.x + threadIdx.x;
    if (i < NN) {
        rowptr[i] = ex[i] + bsum[i >> 10];
        float di = rsqrtf((float)(deg[i] + 1));  // +1 self-loop
        dinv[i] = di;
        float2 xv = ((const float2*)x)[i];
        xn[i] = make_float2(xv.x * di, xv.y * di);
    }
    if (i == 0) rowptr[NN] = NE;
}

// ---------------------------------------------------------------------------
// Bucketed counting sort of edges by dst (bucket = dst>>5, 32 nodes/bucket)
__global__ void k_binit(const int* __restrict__ rowptr, int* __restrict__ cursorB) {
    int b = blockIdx.x * blockDim.x + threadIdx.x;
    if (b < NBUCK) cursorB[b] = rowptr[b << 5];
}

// Pass A: scatter packed (src<<5 | dst&31) into per-bucket contiguous regions
__global__ void k_passA(const void* ei, const int* __restrict__ flag,
                        int* __restrict__ cursorB, unsigned* __restrict__ packed) {
    int e = blockIdx.x * blockDim.x + threadIdx.x;
    if (e >= NE) return;
    int s, d;
    if (*flag == 0) {
        const long long* p = (const long long*)ei;
        s = (int)p[e]; d = (int)p[NE + e];
    } else {
        const int* p = (const int*)ei;
        s = p[e]; d = p[NE + e];
    }
    int b = d >> 5;
    int pos = atomicAdd(&cursorB[b], 1);
    packed[pos] = ((unsigned)s << 5) | (unsigned)(d & 31);
}

// Pass B: per-bucket LDS counting sort -> ssrc in dst-sorted (CSR) order
__global__ __launch_bounds__(256) void k_passB(const int* __restrict__ rowptr,
                                               const unsigned* __restrict__ packed,
                                               int* __restrict__ ssrc) {
    __shared__ int cnt[32];
    __shared__ int rbase[32];
    int b = blockIdx.x;
    int n0 = b << 5;
    if (threadIdx.x < 32) {
        cnt[threadIdx.x] = 0;
        int n = n0 + threadIdx.x;
        rbase[threadIdx.x] = (n < NN) ? rowptr[n] : 0;
    }
    __syncthreads();
    int estart = rowptr[n0];
    int eend = rowptr[min(n0 + 32, NN)];
    for (int i = estart + threadIdx.x; i < eend; i += 256) {
        unsigned pk = packed[i];
        int dl = pk & 31;
        int s = (int)(pk >> 5);
        int r = atomicAdd(&cnt[dl], 1);
        ssrc[rbase[dl] + r] = s;
    }
}

// ---------------------------------------------------------------------------
// Layer 1 fused: agg of xn (2-wide) + 2->64 transform + bias + ReLU.
// h[n][j] = relu( (dinv[n]*(xn[n]+sum xn[src])) . W1[:,j] + b1[j] )
__global__ __launch_bounds__(256) void k_layer1(const int* __restrict__ rowptr,
                                                const int* __restrict__ ssrc,
                                                const float2* __restrict__ xn,
                                                const float* __restrict__ dinv,
                                                const float* __restrict__ W1,
                                                const float* __restrict__ b1,
                                                float* __restrict__ h) {
    int node = blockIdx.x * 4 + (threadIdx.x >> 6);
    if (node >= NN) return;
    int lane = threadIdx.x & 63;
    float2 a = xn[node];  // self loop
    float ax = a.x, ay = a.y;
    int s0 = rowptr[node], e0 = rowptr[node + 1];
    int i = s0;
    for (; i + 2 <= e0; i += 2) {
        float2 v0 = xn[ssrc[i]];
        float2 v1 = xn[ssrc[i + 1]];
        ax += v0.x + v1.x;
        ay += v0.y + v1.y;
    }
    for (; i < e0; ++i) { float2 v = xn[ssrc[i]]; ax += v.x; ay += v.y; }
    float di = dinv[node];
    ax *= di; ay *= di;
    float v = fmaf(ax, W1[lane], fmaf(ay, W1[64 + lane], b1[lane]));
    h[(size_t)node * 64 + lane] = fmaxf(v, 0.f);
}

// 64x64 GEMM transform: t[n][:] = dinv[n] * (h[n][:] @ W)
__global__ __launch_bounds__(256) void k_gemm64(const float* __restrict__ h,
                                                const float* __restrict__ W,
                                                const float* __restrict__ dinv,
                                                float* __restrict__ t) {
    __shared__ float Ws[64 * 64];
    __shared__ float hs[4][64];
    int tx = threadIdx.x & 63, ty = threadIdx.x >> 6;
    for (int i = threadIdx.x; i < 64 * 64; i += 256) Ws[i] = W[i];
    __syncthreads();
    int base = blockIdx.x * 64;
    for (int it = 0; it < 16; ++it) {
        int n = base + it * 4 + ty;
        if (n < NN) hs[ty][tx] = h[(size_t)n * 64 + tx];
        __syncthreads();
        if (n < NN) {
            float acc = 0.f;
#pragma unroll
            for (int k = 0; k < 64; ++k) acc += hs[ty][k] * Ws[k * 64 + tx];
            t[(size_t)n * 64 + tx] = dinv[n] * acc;
        }
        __syncthreads();
    }
}

// 64->1 transform: t3[n] = dinv[n] * dot(h[n][:], W3)
__global__ void k_transform3(const float* __restrict__ h, const float* __restrict__ W3,
                             const float* __restrict__ dinv, float* __restrict__ t3) {
    int tid = blockIdx.x * blockDim.x + threadIdx.x;
    if (tid >= NN * 64) return;
    int n = tid >> 6, k = tid & 63;
    float v = h[(size_t)n * 64 + k] * W3[k];
#pragma unroll
    for (int off = 32; off > 0; off >>= 1) v += __shfl_down(v, off, 64);
    if (k == 0) t3[n] = dinv[n] * v;
}

// ---------------------------------------------------------------------------
// Pull aggregation (64-wide), fused finalize: one 64-lane wave per node.
__global__ __launch_bounds__(256) void k_aggregate(const int* __restrict__ rowptr,
                                                   const int* __restrict__ ssrc,
                                                   const float* __restrict__ t,
                                                   const float* __restrict__ dinv,
                                                   const float* __restrict__ b,
                                                   float* __restrict__ hout, int relu) {
    int node = blockIdx.x * 4 + (threadIdx.x >> 6);
    if (node >= NN) return;
    int lane = threadIdx.x & 63;
    int start = rowptr[node], end = rowptr[node + 1];
    float acc = t[(size_t)node * 64 + lane];  // self loop
    int i = start;
    for (; i + 4 <= end; i += 4) {
        int s0 = ssrc[i], s1 = ssrc[i + 1], s2 = ssrc[i + 2], s3 = ssrc[i + 3];
        float a0 = t[(size_t)s0 * 64 + lane];
        float a1 = t[(size_t)s1 * 64 + lane];
        float a2 = t[(size_t)s2 * 64 + lane];
        float a3 = t[(size_t)s3 * 64 + lane];
        acc += a0 + a1 + a2 + a3;
    }
    for (; i < end; ++i) acc += t[(size_t)ssrc[i] * 64 + lane];
    float v = dinv[node] * acc + b[lane];
    if (relu) v = fmaxf(v, 0.f);
    hout[(size_t)node * 64 + lane] = v;
}

// Scalar variant for the 1-wide last layer: one thread per node.
__global__ void k_aggregate3(const int* __restrict__ rowptr, const int* __restrict__ ssrc,
                             const float* __restrict__ t3, const float* __restrict__ dinv,
                             const float* __restrict__ b3, float* __restrict__ out) {
    int n = blockIdx.x * blockDim.x + threadIdx.x;
    if (n >= NN) return;
    int s = rowptr[n], e = rowptr[n + 1];
    float acc = t3[n];
    int i = s;
    for (; i + 4 <= e; i += 4)
        acc += t3[ssrc[i]] + t3[ssrc[i + 1]] + t3[ssrc[i + 2]] + t3[ssrc[i + 3]];
    for (; i < e; ++i) acc += t3[ssrc[i]];
    out[n] = dinv[n] * acc + b3[0];
}

// ---------------------------------------------------------------------------
extern "C" void kernel_launch(void* const* d_in, const int* in_sizes, int n_in,
                              void* d_out, int out_size, void* d_ws, size_t ws_size,
                              hipStream_t stream) {
    const float* x  = (const float*)d_in[0];
    const void*  ei = d_in[1];
    const float* W1 = (const float*)d_in[2];
    const float* b1 = (const float*)d_in[3];
    const float* W2 = (const float*)d_in[4];
    const float* b2 = (const float*)d_in[5];
    const float* W3 = (const float*)d_in[6];
    const float* b3 = (const float*)d_in[7];
    float* out = (float*)d_out;

    char* ws = (char*)d_ws;
    size_t off = 0;
    auto take = [&](size_t bytes) -> char* {
        char* p = ws + off;
        off = (off + bytes + 255) & ~(size_t)255;
        return p;
    };
    float*    dinv    = (float*)take((size_t)NN * 4);
    int*      deg     = (int*)take((size_t)NN * 4);
    int*      flag    = (int*)take(4);
    int*      ex      = (int*)take((size_t)NN * 4);
    int*      bsum    = (int*)take(128 * 4);
    int*      rowptr  = (int*)take((size_t)(NN + 1) * 4);
    int*      cursorB = (int*)take((size_t)NBUCK * 4);
    unsigned* packed  = (unsigned*)take((size_t)NE * 4);
    int*      ssrc    = (int*)take((size_t)NE * 4);
    float2*   xn      = (float2*)take((size_t)NN * 8);
    float*    tb      = (float*)take((size_t)NN * 64 * 4);
    float*    hb      = (float*)take((size_t)NN * 64 * 4);
    float*    t3      = (float*)take((size_t)NN * 4);

    // --- setup: edge dtype detect, degrees ---
    hipMemsetAsync(flag, 0, 4, stream);
    hipMemsetAsync(deg, 0, (size_t)NN * 4, stream);
    k_detect<<<1024, 256, 0, stream>>>((const unsigned int*)ei, flag);
    k_degree<<<(NE + 255) / 256, 256, 0, stream>>>(ei, flag, deg);

    // --- rowptr scan + dinv + xn ---
    k_scan1<<<NBLK_SCAN, 256, 0, stream>>>(deg, ex, bsum);
    k_scan2<<<1, 128, 0, stream>>>(bsum);
    k_scan3<<<(NN + 255) / 256, 256, 0, stream>>>(ex, bsum, deg, x, rowptr, dinv, xn);

    // --- CSR fill via bucketed counting sort ---
    k_binit<<<(NBUCK + 255) / 256, 256, 0, stream>>>(rowptr, cursorB);
    k_passA<<<(NE + 255) / 256, 256, 0, stream>>>(ei, flag, cursorB, packed);
    k_passB<<<NBUCK, 256, 0, stream>>>(rowptr, packed, ssrc);

    const int nblk_agg = (NN + 3) / 4;  // 4 waves (nodes) per block
    const int nblk_nf  = (NN * 64 + 255) / 256;

    // --- layer 1 (fused 2-wide aggregate + transform) ---
    k_layer1<<<nblk_agg, 256, 0, stream>>>(rowptr, ssrc, xn, dinv, W1, b1, hb);

    // --- layer 2 ---
    k_gemm64<<<(NN + 63) / 64, 256, 0, stream>>>(hb, W2, dinv, tb);
    k_aggregate<<<nblk_agg, 256, 0, stream>>>(rowptr, ssrc, tb, dinv, b2, hb, 1);

    // --- layer 3 ---
    k_transform3<<<nblk_nf, 256, 0, stream>>>(hb, W3, dinv, t3);
    k_aggregate3<<<(NN + 255) / 256, 256, 0, stream>>>(rowptr, ssrc, t3, dinv, b3, out);
}